// Round 5
// baseline (386.024 us; speedup 1.0000x reference)
//
#include <hip/hip_runtime.h>
#include <hip/hip_bf16.h>

typedef unsigned short u16;
typedef unsigned int   u32;
typedef short short8   __attribute__((ext_vector_type(8)));
typedef float floatx4  __attribute__((ext_vector_type(4)));
typedef unsigned short ushort8 __attribute__((ext_vector_type(8)));

#define MFMA(a, b, c) __builtin_amdgcn_mfma_f32_16x16x32_bf16((a), (b), (c), 0, 0, 0)

static __device__ __forceinline__ u16 f2bf(float f) {
  __hip_bfloat16 h = __float2bfloat16(f);
  return *reinterpret_cast<u16*>(&h);
}
static __device__ __forceinline__ float bf2f(u16 u) {
  __hip_bfloat16 h = *reinterpret_cast<__hip_bfloat16*>(&u);
  return __bfloat162float(h);
}

// async global->LDS, 16B per lane; LDS dest must be lane-contiguous (m104/m108)
static __device__ __forceinline__ void gll16(const void* g, void* l) {
  __builtin_amdgcn_global_load_lds(
      (const __attribute__((address_space(1))) u32*)g,
      (__attribute__((address_space(3))) u32*)l, 16, 0, 0);
}

// ---------------------------------------------------------------------------
// Kernel 1: convert x fp32 -> bf16 (8*2048*2048 = 33,554,432 elems)
// ---------------------------------------------------------------------------
__global__ void convert_x_kernel(const float4* __restrict__ x, u16* __restrict__ xb) {
  int idx = blockIdx.x * blockDim.x + threadIdx.x;
  int stride = gridDim.x * blockDim.x;
  for (int i = idx; i < 8388608; i += stride) {
    float4 v = x[i];
    ushort4 o;
    o.x = f2bf(v.x); o.y = f2bf(v.y); o.z = f2bf(v.z); o.w = f2bf(v.w);
    ((ushort4*)xb)[i] = o;
  }
}

// ---------------------------------------------------------------------------
// Kernel 2: Wt[768][2048] bf16 = concat(Wq,Wk,Wv) transposed (LDS transpose)
// ---------------------------------------------------------------------------
__global__ void build_wt_kernel(const float* __restrict__ Wq, const float* __restrict__ Wk,
                                const float* __restrict__ Wv, u16* __restrict__ Wt) {
  __shared__ u16 ls[64][264];
  const int t = threadIdx.x;
  const int k0 = blockIdx.x * 64;
  const int mat = blockIdx.y;
  const float* W = (mat == 0) ? Wq : (mat == 1) ? Wk : Wv;
#pragma unroll
  for (int p = 0; p < 16; ++p) {
    const int r = p * 4 + (t >> 6);
    const int c = (t & 63) * 4;
    float4 w = *(const float4*)(W + (size_t)(k0 + r) * 256 + c);
    ls[r][c] = f2bf(w.x); ls[r][c + 1] = f2bf(w.y);
    ls[r][c + 2] = f2bf(w.z); ls[r][c + 3] = f2bf(w.w);
  }
  __syncthreads();
#pragma unroll
  for (int q = 0; q < 8; ++q) {
    const int n = q * 32 + (t >> 3);
    const int kc = (t & 7) * 8;
    ushort8 v;
#pragma unroll
    for (int j = 0; j < 8; ++j) v[j] = ls[kc + j][n];
    *(ushort8*)(Wt + (size_t)(mat * 256 + n) * 2048 + k0 + kc) = v;
  }
}

// ---------------------------------------------------------------------------
// Kernel 3: QKV GEMM. C[16384,768] = Xb[16384,2048] @ Wt[768,2048]^T  (m97-style)
// ---------------------------------------------------------------------------
__global__ __launch_bounds__(256, 3) void qkv_gemm_kernel(
    const u16* __restrict__ xb, const u16* __restrict__ Wt,
    const float* __restrict__ bq, const float* __restrict__ bk, const float* __restrict__ bv,
    u16* __restrict__ qws, u16* __restrict__ kws, u16* __restrict__ vws) {
  __shared__ __align__(16) u16 As[128 * 32];
  __shared__ __align__(16) u16 Bs[128 * 32];
  const int t = threadIdx.x;
  const int lane = t & 63, w = t >> 6;
  const int ln = lane & 15, quad = lane >> 4;
  const int wm = w >> 1, wn = w & 1;
  const int m0 = blockIdx.x * 128;
  const int n0 = blockIdx.y * 128;

  const int rowS = t >> 2, cS = t & 3;
  const u16* pa0 = xb + (size_t)(m0 + rowS) * 2048 + cS * 8;
  const u16* pb0 = Wt + (size_t)(n0 + rowS) * 2048 + cS * 8;

  floatx4 acc[4][4] = {};

  for (int kt = 0; kt < 64; ++kt) {
    const int ko = kt * 32;
    gll16(pa0 + ko,               As + (size_t)t * 8);
    gll16(pa0 + ko + 64 * 2048,   As + (size_t)(t + 256) * 8);
    gll16(pb0 + ko,               Bs + (size_t)t * 8);
    gll16(pb0 + ko + 64 * 2048,   Bs + (size_t)(t + 256) * 8);
    __syncthreads();

    short8 af[4], bf[4];
#pragma unroll
    for (int rt = 0; rt < 4; ++rt)
      af[rt] = *(const short8*)&As[(wm * 64 + rt * 16 + ln) * 32 + quad * 8];
#pragma unroll
    for (int ct = 0; ct < 4; ++ct)
      bf[ct] = *(const short8*)&Bs[(wn * 64 + ct * 16 + ln) * 32 + quad * 8];
#pragma unroll
    for (int rt = 0; rt < 4; ++rt)
#pragma unroll
      for (int ct = 0; ct < 4; ++ct)
        acc[rt][ct] = MFMA(af[rt], bf[ct], acc[rt][ct]);
    __syncthreads();
  }

  const int region = n0 >> 8;  // 0=q 1=k 2=v
  u16* dst = (region == 0) ? qws : (region == 1) ? kws : vws;
  const float* bias_p = (region == 0) ? bq : (region == 1) ? bk : bv;
#pragma unroll
  for (int rt = 0; rt < 4; ++rt) {
    const int mg = m0 + wm * 64 + rt * 16 + quad * 4;
#pragma unroll
    for (int ct = 0; ct < 4; ++ct) {
      const int nc = (n0 + wn * 64 + ct * 16 + ln) & 255;
      const float bias = bias_p[nc];
#pragma unroll
      for (int i = 0; i < 4; ++i) {
        const int m = mg + i;
        dst[(size_t)m * 256 + nc] = f2bf(acc[rt][ct][i] + bias);
      }
    }
  }
}

// ---------------------------------------------------------------------------
// Kernel 3b: transpose v[16384][256] -> vt[8][256][2048] (LDS-tiled, coalesced)
// ---------------------------------------------------------------------------
__global__ void transpose_v_kernel(const u16* __restrict__ v, u16* __restrict__ vt) {
  __shared__ u16 ls[64][74];
  const int t = threadIdx.x;
  const int n0 = blockIdx.x * 64, d0 = blockIdx.y * 64, b = blockIdx.z;
  const int r = t >> 3, c8 = (t & 7) * 8;
#pragma unroll
  for (int p = 0; p < 2; ++p) {
    const int row = p * 32 + r;
    ushort8 d = *(const ushort8*)(v + (size_t)(b * 2048 + n0 + row) * 256 + d0 + c8);
#pragma unroll
    for (int j = 0; j < 8; ++j) ls[row][c8 + j] = d[j];
  }
  __syncthreads();
#pragma unroll
  for (int p = 0; p < 2; ++p) {
    const int d = p * 32 + r;
    ushort8 o;
#pragma unroll
    for (int j = 0; j < 8; ++j) o[j] = ls[c8 + j][d];
    *(ushort8*)(vt + (size_t)(b * 256 + d0 + d) * 2048 + n0 + c8) = o;
  }
}

// ---------------------------------------------------------------------------
// Kernel 4: fused attention, key-split 2, async staging, 4x1 wave split.
// Wave w owns a DISJOINT 16-key stripe in S (8 B-frags/iter, each feeding
// 4 row-MFMAs) and a disjoint 64-wide d stripe in PV -> 96 b128 LDS reads
// per block-iter (was 144). Each wave holds all 64 q-rows (qf = 128 VGPR).
// Denominators: 8 partials (2 ks x 4 waves), summed in combine.
// ---------------------------------------------------------------------------
__global__ __launch_bounds__(256, 2) void attn_kernel(
    const u16* __restrict__ qws, const u16* __restrict__ kws,
    const u16* __restrict__ vtws, float* __restrict__ po0,
    float* __restrict__ po1, float* __restrict__ pd) {
  extern __shared__ __align__(16) u16 smem[];
  u16* kbuf = smem;                        // 64 keys x 256 feat  (32 KB)
  u16* vbuf = smem + 64 * 256;             // 256 d   x 64 keys   (32 KB)
  u16* pbuf = smem + 64 * 256 + 256 * 64;  // 64 rows x 64 keys   (8 KB)

  const int t = threadIdx.x;
  const int lane = t & 63, w = t >> 6;
  const int ln = lane & 15, quad = lane >> 4;
  const int sw = ln & 7;
  const int g = blockIdx.x;                // group = b*2 + ks
  const int b = g >> 1;
  const int ks = g & 1;
  const int q0 = blockIdx.y * 64;
  float* po = ks ? po1 : po0;

  // persistent Q fragments: ALL 64 rows per wave (A-layout: m=ln, k=quad*8+j)
  short8 qf[4][8];
  const u16* qbase = qws + ((size_t)(b * 2048 + q0)) * 256;
#pragma unroll
  for (int rf = 0; rf < 4; ++rf)
#pragma unroll
    for (int kk = 0; kk < 8; ++kk)
      qf[rf][kk] = *(const short8*)(qbase + (size_t)(rf * 16 + ln) * 256 + kk * 32 + quad * 8);

  floatx4 of[4][4] = {};
  float pdn[4][4] = {};

  const u16* kbase = kws + ((size_t)(b * 2048 + ks * 1024)) * 256;
  const u16* vbase = vtws + ((size_t)b * 256) * 2048;
  const int coff0 = ks * 1024;
  const int rk = t >> 5, ck = t & 31;   // k staging coords
  const int rv = t >> 3, cv = t & 7;    // v staging coords

#define STAGE_K(KT)                                                          \
  _Pragma("unroll")                                                          \
  for (int j = 0; j < 8; ++j) {                                              \
    const int row = j * 8 + rk;                                              \
    const int colg = ck ^ (row & 7);                                         \
    gll16(kbase + (((size_t)((KT) * 64 + row)) << 8) + colg * 8,             \
          kbuf + (((size_t)(j * 256 + t)) << 3));                            \
  }
#define STAGE_V(KT)                                                          \
  _Pragma("unroll")                                                          \
  for (int j = 0; j < 8; ++j) {                                              \
    const int row = j * 32 + rv;                                             \
    const int colg = cv ^ (row & 7);                                         \
    gll16(vbase + ((size_t)row << 11) + coff0 + (KT) * 64 + colg * 8,        \
          vbuf + (((size_t)(j * 256 + t)) << 3));                            \
  }

  STAGE_K(0)
  STAGE_V(0)

  const int key = w * 16 + ln;             // wave's key stripe (S phase)
  const int kc = key >> 3, klow = key & 7; // pbuf write coords

  for (int kt = 0; kt < 16; ++kt) {
    __syncthreads();  // bar1: staged tiles visible (drains vmcnt)

    // ---- S = Q K^T : wave computes S[64 rows][16 keys] ----
    floatx4 sacc[4] = {};
#pragma unroll
    for (int kk = 0; kk < 8; ++kk) {
      const int cr = (kk << 2) + quad;
      short8 bfr = *(const short8*)&kbuf[(key << 8) + ((cr ^ sw) << 3)];
      sacc[0] = MFMA(qf[0][kk], bfr, sacc[0]);
      sacc[1] = MFMA(qf[1][kk], bfr, sacc[1]);
      sacc[2] = MFMA(qf[2][kk], bfr, sacc[2]);
      sacc[3] = MFMA(qf[3][kk], bfr, sacc[3]);
    }

    // ---- p = exp(sigmoid(s)/16) via cubic; row sums; write P ----
#pragma unroll
    for (int rt = 0; rt < 4; ++rt) {
#pragma unroll
      for (int i = 0; i < 4; ++i) {
        const float s = sacc[rt][i];
        const float sig = __builtin_amdgcn_rcpf(1.f + __expf(-s));
        const float z = 0.0625f * sig;
        // exp(z) on [0,1/16]: cubic, max rel err ~6e-7 (<< bf16 ulp)
        const float p = 1.f + z * (1.f + z * (0.5f + z * 0.16666667f));
        const u16 pb = f2bf(p);
        float v = bf2f(pb);
        const int rowl = rt * 16 + (quad << 2) + i;
        pbuf[(rowl << 6) + ((kc ^ (rowl & 7)) << 3) + klow] = pb;
        v += __shfl_xor(v, 1); v += __shfl_xor(v, 2);
        v += __shfl_xor(v, 4); v += __shfl_xor(v, 8);
        pdn[rt][i] += v;   // sum over this wave's 16 keys
      }
    }
    __syncthreads();  // bar2: pbuf visible; all waves past kbuf reads

    if (kt < 15) { STAGE_K(kt + 1) }  // overlap K-load with PV compute

    // ---- O += P V : wave computes O[64 rows][64 d stripe] ----
#pragma unroll
    for (int ksi = 0; ksi < 2; ++ksi) {
      const int cr = (ksi << 2) + quad;
      short8 vb[4];
#pragma unroll
      for (int df = 0; df < 4; ++df) {
        const int dr = w * 64 + df * 16 + ln;
        vb[df] = *(const short8*)&vbuf[(dr << 6) + ((cr ^ sw) << 3)];
      }
#pragma unroll
      for (int rf = 0; rf < 4; ++rf) {
        const int rA = rf * 16 + ln;
        short8 a = *(const short8*)&pbuf[(rA << 6) + ((cr ^ sw) << 3)];
#pragma unroll
        for (int df = 0; df < 4; ++df)
          of[rf][df] = MFMA(a, vb[df], of[rf][df]);
      }
    }
    __syncthreads();  // bar3: vbuf/pbuf reads done before restage

    if (kt < 15) { STAGE_V(kt + 1) }
  }

  // ---- epilogue: write unnormalized partial O + per-wave denominators ----
#pragma unroll
  for (int rf = 0; rf < 4; ++rf) {
#pragma unroll
    for (int i = 0; i < 4; ++i) {
      const int rowl = rf * 16 + (quad << 2) + i;
      float* orow = po + ((size_t)(b * 2048 + q0 + rowl)) * 256 + w * 64 + ln;
#pragma unroll
      for (int df = 0; df < 4; ++df)
        orow[df * 16] = of[rf][df][i];
      if (ln == 0)
        pd[(size_t)(ks * 4 + w) * 16384 + b * 2048 + q0 + rowl] = pdn[rf][i];
    }
  }
#undef STAGE_K
#undef STAGE_V
}

// ---------------------------------------------------------------------------
// Kernel 5: combine — out = (po0 + po1) / sum_{j=0..7} pd[j]
// ---------------------------------------------------------------------------
__global__ void combine_kernel(const float4* __restrict__ po0, const float4* __restrict__ po1,
                               const float* __restrict__ pd, float4* __restrict__ out) {
  const int i = blockIdx.x * 256 + threadIdx.x;   // over 1,048,576 float4s
  const int row = i >> 6;
  float den = 0.f;
#pragma unroll
  for (int j = 0; j < 8; ++j) den += pd[row + j * 16384];
  const float inv = 1.0f / den;
  float4 a = po0[i], b = po1[i];
  float4 o;
  o.x = (a.x + b.x) * inv; o.y = (a.y + b.y) * inv;
  o.z = (a.z + b.z) * inv; o.w = (a.w + b.w) * inv;
  out[i] = o;
}

// ---------------------------------------------------------------------------
// launch
// ---------------------------------------------------------------------------
extern "C" void kernel_launch(void* const* d_in, const int* in_sizes, int n_in,
                              void* d_out, int out_size, void* d_ws, size_t ws_size,
                              hipStream_t stream) {
  const float* x  = (const float*)d_in[0];
  const float* Wq = (const float*)d_in[1];
  const float* bq = (const float*)d_in[2];
  const float* Wk = (const float*)d_in[3];
  const float* bk = (const float*)d_in[4];
  const float* Wv = (const float*)d_in[5];
  const float* bv = (const float*)d_in[6];
  float* out = (float*)d_out;

  char* ws = (char*)d_ws;
  // ws layout (bytes):
  //   xb 67108864 | Wt 3145728 | q 8388608 | k 8388608 | v 8388608 | vt 8388608
  // attn partials REUSE the xb region (dead after GEMM):
  //   po0 @ 0 (16.78 MB) | po1 @ 16777216 | pd @ 33554432 (512 KB)
  u16* xb   = (u16*)(ws);
  u16* Wt   = (u16*)(ws + 67108864);
  u16* qws  = (u16*)(ws + 70254592);
  u16* kws  = (u16*)(ws + 78643200);
  u16* vws  = (u16*)(ws + 87031808);
  u16* vtws = (u16*)(ws + 95420416);   // total 103,809,024 B
  float* po0 = (float*)(ws);
  float* po1 = (float*)(ws + 16777216);
  float* pd  = (float*)(ws + 33554432);

  convert_x_kernel<<<4096, 256, 0, stream>>>((const float4*)x, xb);
  build_wt_kernel<<<dim3(32, 3), 256, 0, stream>>>(Wq, Wk, Wv, Wt);
  qkv_gemm_kernel<<<dim3(128, 6), 256, 0, stream>>>(xb, Wt, bq, bk, bv, qws, kws, vws);
  transpose_v_kernel<<<dim3(32, 4, 8), 256, 0, stream>>>(vws, vtws);

  hipFuncSetAttribute(reinterpret_cast<const void*>(attn_kernel),
                      hipFuncAttributeMaxDynamicSharedMemorySize, 73728);
  attn_kernel<<<dim3(16, 32), 256, 73728, stream>>>(qws, kws, vtws, po0, po1, pd);
  combine_kernel<<<4096, 256, 0, stream>>>((const float4*)po0, (const float4*)po1, pd, (float4*)out);
}

// Round 6
// 331.436 us; speedup vs baseline: 1.1647x; 1.1647x over previous
//
#include <hip/hip_runtime.h>
#include <hip/hip_bf16.h>

typedef unsigned short u16;
typedef unsigned int   u32;
typedef short short8   __attribute__((ext_vector_type(8)));
typedef float floatx4  __attribute__((ext_vector_type(4)));
typedef unsigned short ushort8 __attribute__((ext_vector_type(8)));

#define MFMA(a, b, c) __builtin_amdgcn_mfma_f32_16x16x32_bf16((a), (b), (c), 0, 0, 0)

static __device__ __forceinline__ u16 f2bf(float f) {
  __hip_bfloat16 h = __float2bfloat16(f);
  return *reinterpret_cast<u16*>(&h);
}
static __device__ __forceinline__ float bf2f(u16 u) {
  __hip_bfloat16 h = *reinterpret_cast<__hip_bfloat16*>(&u);
  return __bfloat162float(h);
}

// async global->LDS, 16B per lane; LDS dest must be lane-contiguous (m104/m108)
static __device__ __forceinline__ void gll16(const void* g, void* l) {
  __builtin_amdgcn_global_load_lds(
      (const __attribute__((address_space(1))) u32*)g,
      (__attribute__((address_space(3))) u32*)l, 16, 0, 0);
}

// ---------------------------------------------------------------------------
// Kernel 2: Wt[768][2048] bf16 = concat(Wq,Wk,Wv) transposed (LDS transpose)
// ---------------------------------------------------------------------------
__global__ void build_wt_kernel(const float* __restrict__ Wq, const float* __restrict__ Wk,
                                const float* __restrict__ Wv, u16* __restrict__ Wt) {
  __shared__ u16 ls[64][264];
  const int t = threadIdx.x;
  const int k0 = blockIdx.x * 64;
  const int mat = blockIdx.y;
  const float* W = (mat == 0) ? Wq : (mat == 1) ? Wk : Wv;
#pragma unroll
  for (int p = 0; p < 16; ++p) {
    const int r = p * 4 + (t >> 6);
    const int c = (t & 63) * 4;
    float4 w = *(const float4*)(W + (size_t)(k0 + r) * 256 + c);
    ls[r][c] = f2bf(w.x); ls[r][c + 1] = f2bf(w.y);
    ls[r][c + 2] = f2bf(w.z); ls[r][c + 3] = f2bf(w.w);
  }
  __syncthreads();
#pragma unroll
  for (int q = 0; q < 8; ++q) {
    const int n = q * 32 + (t >> 3);
    const int kc = (t & 7) * 8;
    ushort8 v;
#pragma unroll
    for (int j = 0; j < 8; ++j) v[j] = ls[kc + j][n];
    *(ushort8*)(Wt + (size_t)(mat * 256 + n) * 2048 + k0 + kc) = v;
  }
}

// ---------------------------------------------------------------------------
// Kernel 3: QKV GEMM with FUSED fp32->bf16 convert on the A (x) operand.
// C[16384,768] = cvt(x[16384,2048]) @ Wt[768,2048]^T. A staged via fp32
// loads + in-register convert + ds_write (x fits L3; 6x n-block re-reads
// stay on-XCD since 128%8==0 -> all n-blocks of an m-slab share an XCD).
// B staged via global_load_lds width-16 as before.
// ---------------------------------------------------------------------------
__global__ __launch_bounds__(256, 3) void qkv_gemm_kernel(
    const float* __restrict__ x, const u16* __restrict__ Wt,
    const float* __restrict__ bq, const float* __restrict__ bk, const float* __restrict__ bv,
    u16* __restrict__ qws, u16* __restrict__ kws, u16* __restrict__ vws) {
  __shared__ __align__(16) u16 As[128 * 32];
  __shared__ __align__(16) u16 Bs[128 * 32];
  const int t = threadIdx.x;
  const int lane = t & 63, w = t >> 6;
  const int ln = lane & 15, quad = lane >> 4;
  const int wm = w >> 1, wn = w & 1;
  const int m0 = blockIdx.x * 128;
  const int n0 = blockIdx.y * 128;

  const int rowS = t >> 2, cS = t & 3;
  const float* pa0 = x + (size_t)(m0 + rowS) * 2048 + cS * 8;
  const u16*   pb0 = Wt + (size_t)(n0 + rowS) * 2048 + cS * 8;

  floatx4 acc[4][4] = {};

  for (int kt = 0; kt < 64; ++kt) {
    const int ko = kt * 32;
    // B: async DMA to LDS
    gll16(pb0 + ko,               Bs + (size_t)t * 8);
    gll16(pb0 + ko + 64 * 2048,   Bs + (size_t)(t + 256) * 8);
    // A: fp32 load -> cvt -> LDS (fused convert)
    float4 a0 = *(const float4*)(pa0 + ko);
    float4 a1 = *(const float4*)(pa0 + ko + 4);
    float4 a2 = *(const float4*)(pa0 + ko + 64 * 2048);
    float4 a3 = *(const float4*)(pa0 + ko + 64 * 2048 + 4);
    ushort8 c0, c1;
    c0[0] = f2bf(a0.x); c0[1] = f2bf(a0.y); c0[2] = f2bf(a0.z); c0[3] = f2bf(a0.w);
    c0[4] = f2bf(a1.x); c0[5] = f2bf(a1.y); c0[6] = f2bf(a1.z); c0[7] = f2bf(a1.w);
    c1[0] = f2bf(a2.x); c1[1] = f2bf(a2.y); c1[2] = f2bf(a2.z); c1[3] = f2bf(a2.w);
    c1[4] = f2bf(a3.x); c1[5] = f2bf(a3.y); c1[6] = f2bf(a3.z); c1[7] = f2bf(a3.w);
    *(ushort8*)&As[(size_t)t * 8]         = c0;
    *(ushort8*)&As[(size_t)(t + 256) * 8] = c1;
    __syncthreads();

    short8 af[4], bf[4];
#pragma unroll
    for (int rt = 0; rt < 4; ++rt)
      af[rt] = *(const short8*)&As[(wm * 64 + rt * 16 + ln) * 32 + quad * 8];
#pragma unroll
    for (int ct = 0; ct < 4; ++ct)
      bf[ct] = *(const short8*)&Bs[(wn * 64 + ct * 16 + ln) * 32 + quad * 8];
#pragma unroll
    for (int rt = 0; rt < 4; ++rt)
#pragma unroll
      for (int ct = 0; ct < 4; ++ct)
        acc[rt][ct] = MFMA(af[rt], bf[ct], acc[rt][ct]);
    __syncthreads();
  }

  const int region = n0 >> 8;  // 0=q 1=k 2=v
  u16* dst = (region == 0) ? qws : (region == 1) ? kws : vws;
  const float* bias_p = (region == 0) ? bq : (region == 1) ? bk : bv;
#pragma unroll
  for (int rt = 0; rt < 4; ++rt) {
    const int mg = m0 + wm * 64 + rt * 16 + quad * 4;
#pragma unroll
    for (int ct = 0; ct < 4; ++ct) {
      const int nc = (n0 + wn * 64 + ct * 16 + ln) & 255;
      const float bias = bias_p[nc];
#pragma unroll
      for (int i = 0; i < 4; ++i) {
        const int m = mg + i;
        dst[(size_t)m * 256 + nc] = f2bf(acc[rt][ct][i] + bias);
      }
    }
  }
}

// ---------------------------------------------------------------------------
// Kernel 3b: transpose v[16384][256] -> vt[8][256][2048] (LDS-tiled, coalesced)
// ---------------------------------------------------------------------------
__global__ void transpose_v_kernel(const u16* __restrict__ v, u16* __restrict__ vt) {
  __shared__ u16 ls[64][74];
  const int t = threadIdx.x;
  const int n0 = blockIdx.x * 64, d0 = blockIdx.y * 64, b = blockIdx.z;
  const int r = t >> 3, c8 = (t & 7) * 8;
#pragma unroll
  for (int p = 0; p < 2; ++p) {
    const int row = p * 32 + r;
    ushort8 d = *(const ushort8*)(v + (size_t)(b * 2048 + n0 + row) * 256 + d0 + c8);
#pragma unroll
    for (int j = 0; j < 8; ++j) ls[row][c8 + j] = d[j];
  }
  __syncthreads();
#pragma unroll
  for (int p = 0; p < 2; ++p) {
    const int d = p * 32 + r;
    ushort8 o;
#pragma unroll
    for (int j = 0; j < 8; ++j) o[j] = ls[c8 + j][d];
    *(ushort8*)(vt + (size_t)(b * 256 + d0 + d) * 2048 + n0 + c8) = o;
  }
}

// ---------------------------------------------------------------------------
// Kernel 4: fused attention — R4's measured-best 2x2 wave split (qf=64 VGPR,
// no spill) + cubic exp (validated in R5, absmax unchanged). Key-split 2,
// async source-swizzled global_load_lds staging, XCD-grouped dispatch.
// ---------------------------------------------------------------------------
__global__ __launch_bounds__(256, 2) void attn_kernel(
    const u16* __restrict__ qws, const u16* __restrict__ kws,
    const u16* __restrict__ vtws, float* __restrict__ po0,
    float* __restrict__ po1, float* __restrict__ pd) {
  extern __shared__ __align__(16) u16 smem[];
  u16* kbuf = smem;                        // 64 keys x 256 feat  (32 KB)
  u16* vbuf = smem + 64 * 256;             // 256 d   x 64 keys   (32 KB)
  u16* pbuf = smem + 64 * 256 + 256 * 64;  // 64 rows x 64 keys   (8 KB)

  const int t = threadIdx.x;
  const int lane = t & 63, w = t >> 6;
  const int ln = lane & 15, quad = lane >> 4;
  const int wq = w >> 1, wk = w & 1;
  const int sw = ln & 7;
  const int g = blockIdx.x;                // group = b*2 + ks
  const int b = g >> 1;
  const int ks = g & 1;
  const int q0 = blockIdx.y * 64;
  float* po = ks ? po1 : po0;

  // persistent Q fragments (A-layout: m=ln, k=quad*8+j) — 64 VGPRs/wave
  short8 qf[2][8];
  const u16* qbase = qws + ((size_t)(b * 2048 + q0 + wq * 32)) * 256;
#pragma unroll
  for (int rt = 0; rt < 2; ++rt)
#pragma unroll
    for (int kk = 0; kk < 8; ++kk)
      qf[rt][kk] = *(const short8*)(qbase + (size_t)(rt * 16 + ln) * 256 + kk * 32 + quad * 8);

  floatx4 of[2][8] = {};
  float pdn[2][4] = {};

  const u16* kbase = kws + ((size_t)(b * 2048 + ks * 1024)) * 256;
  const u16* vbase = vtws + ((size_t)b * 256) * 2048;
  const int coff0 = ks * 1024;
  const int rk = t >> 5, ck = t & 31;   // k staging coords
  const int rv = t >> 3, cv = t & 7;    // v staging coords

#define STAGE_K(KT)                                                          \
  _Pragma("unroll")                                                          \
  for (int j = 0; j < 8; ++j) {                                              \
    const int row = j * 8 + rk;                                              \
    const int colg = ck ^ (row & 7);                                         \
    gll16(kbase + (((size_t)((KT) * 64 + row)) << 8) + colg * 8,             \
          kbuf + (((size_t)(j * 256 + t)) << 3));                            \
  }
#define STAGE_V(KT)                                                          \
  _Pragma("unroll")                                                          \
  for (int j = 0; j < 8; ++j) {                                              \
    const int row = j * 32 + rv;                                             \
    const int colg = cv ^ (row & 7);                                         \
    gll16(vbase + ((size_t)row << 11) + coff0 + (KT) * 64 + colg * 8,        \
          vbuf + (((size_t)(j * 256 + t)) << 3));                            \
  }

  STAGE_K(0)
  STAGE_V(0)

  for (int kt = 0; kt < 16; ++kt) {
    __syncthreads();  // bar1: staged tiles visible (drains vmcnt)

    // ---- S = Q K^T : wave computes S[32 rows][32 keys] ----
    floatx4 sacc[2][2] = {};
    const int key0 = wk * 32 + ln, key1 = key0 + 16;
#pragma unroll
    for (int kk = 0; kk < 8; ++kk) {
      const int cr = (kk << 2) + quad;
      short8 b0 = *(const short8*)&kbuf[(key0 << 8) + ((cr ^ sw) << 3)];
      short8 b1 = *(const short8*)&kbuf[(key1 << 8) + ((cr ^ sw) << 3)];
      sacc[0][0] = MFMA(qf[0][kk], b0, sacc[0][0]);
      sacc[1][0] = MFMA(qf[1][kk], b0, sacc[1][0]);
      sacc[0][1] = MFMA(qf[0][kk], b1, sacc[0][1]);
      sacc[1][1] = MFMA(qf[1][kk], b1, sacc[1][1]);
    }

    // ---- p = exp(sigmoid(s)/16) via cubic; row sums; write P ----
#pragma unroll
    for (int rt = 0; rt < 2; ++rt) {
      float rs[4] = {0.f, 0.f, 0.f, 0.f};
#pragma unroll
      for (int ct = 0; ct < 2; ++ct) {
        const int keyl = wk * 32 + ct * 16 + ln;
        const int kc = keyl >> 3, klow = keyl & 7;
#pragma unroll
        for (int i = 0; i < 4; ++i) {
          const float s = sacc[rt][ct][i];
          const float sig = __builtin_amdgcn_rcpf(1.f + __expf(-s));
          const float z = 0.0625f * sig;
          // exp(z) on [0,1/16]: cubic, max rel err ~6e-7 (<< bf16 ulp)
          const float p = 1.f + z * (1.f + z * (0.5f + z * 0.16666667f));
          const u16 pb = f2bf(p);
          rs[i] += bf2f(pb);
          const int rowl = wq * 32 + rt * 16 + (quad << 2) + i;
          pbuf[(rowl << 6) + ((kc ^ (rowl & 7)) << 3) + klow] = pb;
        }
      }
#pragma unroll
      for (int i = 0; i < 4; ++i) {
        float v = rs[i];
        v += __shfl_xor(v, 1); v += __shfl_xor(v, 2);
        v += __shfl_xor(v, 4); v += __shfl_xor(v, 8);
        pdn[rt][i] += v;
      }
    }
    __syncthreads();  // bar2: pbuf visible; all waves past kbuf reads

    if (kt < 15) { STAGE_K(kt + 1) }  // overlap K-load with PV compute

    // ---- O += P V : wave computes O[32 rows][128 d (wk half)] ----
    const int rA0 = wq * 32 + ln, rA1 = rA0 + 16;
#pragma unroll
    for (int ksi = 0; ksi < 2; ++ksi) {
      const int cr = (ksi << 2) + quad;
      short8 a0 = *(const short8*)&pbuf[(rA0 << 6) + ((cr ^ sw) << 3)];
      short8 a1 = *(const short8*)&pbuf[(rA1 << 6) + ((cr ^ sw) << 3)];
#pragma unroll
      for (int dt = 0; dt < 8; ++dt) {
        const int dr = wk * 128 + dt * 16 + ln;
        short8 vb = *(const short8*)&vbuf[(dr << 6) + ((cr ^ sw) << 3)];
        of[0][dt] = MFMA(a0, vb, of[0][dt]);
        of[1][dt] = MFMA(a1, vb, of[1][dt]);
      }
    }
    __syncthreads();  // bar3: vbuf/pbuf reads done before restage

    if (kt < 15) { STAGE_V(kt + 1) }
  }

  // ---- epilogue: write unnormalized partial O + denominators ----
#pragma unroll
  for (int rt = 0; rt < 2; ++rt) {
#pragma unroll
    for (int i = 0; i < 4; ++i) {
      const int rowl = wq * 32 + rt * 16 + (quad << 2) + i;
      float* orow = po + ((size_t)(b * 2048 + q0 + rowl)) * 256 + wk * 128 + ln;
#pragma unroll
      for (int dt = 0; dt < 8; ++dt)
        orow[dt * 16] = of[rt][dt][i];
      if (ln == 0)
        pd[(size_t)(ks * 2 + wk) * 16384 + b * 2048 + q0 + rowl] = pdn[rt][i];
    }
  }
#undef STAGE_K
#undef STAGE_V
}

// ---------------------------------------------------------------------------
// Kernel 5: combine — out = (po0 + po1) / sum_{j=0..3} pd[j]
// ---------------------------------------------------------------------------
__global__ void combine_kernel(const float4* __restrict__ po0, const float4* __restrict__ po1,
                               const float* __restrict__ pd, float4* __restrict__ out) {
  const int i = blockIdx.x * 256 + threadIdx.x;   // over 1,048,576 float4s
  const int row = i >> 6;
  const float den = pd[row] + pd[row + 16384] + pd[row + 32768] + pd[row + 49152];
  const float inv = 1.0f / den;
  float4 a = po0[i], b = po1[i];
  float4 o;
  o.x = (a.x + b.x) * inv; o.y = (a.y + b.y) * inv;
  o.z = (a.z + b.z) * inv; o.w = (a.w + b.w) * inv;
  out[i] = o;
}

// ---------------------------------------------------------------------------
// launch
// ---------------------------------------------------------------------------
extern "C" void kernel_launch(void* const* d_in, const int* in_sizes, int n_in,
                              void* d_out, int out_size, void* d_ws, size_t ws_size,
                              hipStream_t stream) {
  const float* x  = (const float*)d_in[0];
  const float* Wq = (const float*)d_in[1];
  const float* bq = (const float*)d_in[2];
  const float* Wk = (const float*)d_in[3];
  const float* bk = (const float*)d_in[4];
  const float* Wv = (const float*)d_in[5];
  const float* bv = (const float*)d_in[6];
  float* out = (float*)d_out;

  char* ws = (char*)d_ws;
  // ws layout (bytes):
  //   scratch/partials 67108864 | Wt 3145728 | q 8388608 | k 8388608 | v 8388608 | vt 8388608
  //   po0 @ 0 (16.78 MB) | po1 @ 16777216 | pd @ 33554432 (256 KB)
  u16* Wt   = (u16*)(ws + 67108864);
  u16* qws  = (u16*)(ws + 70254592);
  u16* kws  = (u16*)(ws + 78643200);
  u16* vws  = (u16*)(ws + 87031808);
  u16* vtws = (u16*)(ws + 95420416);   // total 103,809,024 B
  float* po0 = (float*)(ws);
  float* po1 = (float*)(ws + 16777216);
  float* pd  = (float*)(ws + 33554432);

  build_wt_kernel<<<dim3(32, 3), 256, 0, stream>>>(Wq, Wk, Wv, Wt);
  qkv_gemm_kernel<<<dim3(128, 6), 256, 0, stream>>>(x, Wt, bq, bk, bv, qws, kws, vws);
  transpose_v_kernel<<<dim3(32, 4, 8), 256, 0, stream>>>(vws, vtws);

  hipFuncSetAttribute(reinterpret_cast<const void*>(attn_kernel),
                      hipFuncAttributeMaxDynamicSharedMemorySize, 73728);
  attn_kernel<<<dim3(16, 32), 256, 73728, stream>>>(qws, kws, vtws, po0, po1, pd);
  combine_kernel<<<4096, 256, 0, stream>>>((const float4*)po0, (const float4*)po1, pd, (float4*)out);
}